// Round 1
// 1933.494 us; speedup vs baseline: 1.0553x; 1.0553x over previous
//
#include <hip/hip_runtime.h>
#include <math.h>

typedef float  f32x4  __attribute__((ext_vector_type(4)));
typedef short  short8v __attribute__((ext_vector_type(8)));
typedef unsigned short ushort8v __attribute__((ext_vector_type(8)));
typedef unsigned short ushort4v __attribute__((ext_vector_type(4)));

#define KP_PRE 3840
#define KP_HS  1536

#define WAITV(N) asm volatile("s_waitcnt vmcnt(" #N ")" ::: "memory")
#define SBAR()   asm volatile("s_barrier" ::: "memory")

// ---------------- persistent device state ----------------------------------
__device__ unsigned short g_Xb[16384][3840];  // pre A (x split-6, swizzled)
__device__ unsigned short g_Wb[2048][3840];   // pre B^T (kernel split-6)
__device__ unsigned short g_Rb[2048][1536];   // z   B^T (rec_kernel, 3 j-splits)
__device__ unsigned short g_hs[2][512][1536]; // h 3 i-splits, ping-pong
__device__ float g_pre[16384][2048];          // x@K + bias (gate-interleaved)
__device__ float g_hf[2][512 * 512];          // h f32, ping-pong
__device__ float g_swT[128][512];             // softmax_w transposed
__device__ float g_bperm[2048];               // bias, gate-interleaved cols
__device__ float g_plv[2][512 * 8];
__device__ int   g_pli[2][512 * 8];
__device__ unsigned g_cnt[128];
__device__ unsigned g_release;

__global__ void init_counters()
{
    int t = threadIdx.x;
    if (t < 8) g_cnt[t * 16] = 0u;
    if (t == 8) g_release = 0u;
}

// ---------------- helpers ---------------------------------------------------
__device__ __forceinline__ unsigned short f2bf(float f) {
    unsigned u = __float_as_uint(f);
    return (unsigned short)((u + 0x7fffu + ((u >> 16) & 1u)) >> 16);
}
__device__ __forceinline__ float bf2f(unsigned short s) {
    return __uint_as_float(((unsigned)s) << 16);
}
__device__ __forceinline__ float sigf(float x) { return 1.f / (1.f + expf(-x)); }

__device__ __forceinline__ void split3(float v, unsigned short& s0,
                                       unsigned short& s1, unsigned short& s2) {
    s0 = f2bf(v); float f0 = bf2f(s0);
    s1 = f2bf(v - f0); float f1 = bf2f(s1);
    s2 = f2bf(v - f0 - f1);
}

// pair tables: products split_i(A) * split_j(B), i+j <= 2
__device__ __constant__ int c_ipt[6] = {0, 0, 1, 0, 1, 2};
__device__ __constant__ int c_jpt[6] = {0, 1, 0, 2, 1, 0};

__device__ __forceinline__ void gl16(const unsigned short* g, unsigned short* l) {
    __builtin_amdgcn_global_load_lds((const __attribute__((address_space(1))) void*)g,
                                     (__attribute__((address_space(3))) void*)l, 16, 0, 0);
}

// LDS tile: [rows][64] bf16, row = 128B, 16B-units XOR-swizzled by (row&7)
__device__ __forceinline__ short8v fragld(const unsigned short* sh, int row, int uw) {
    return *(const short8v*)(sh + row * 64 + ((uw ^ (row & 7)) << 3));
}

// stage one BK=64 chunk into ring slot: A = AUNITS*16B, B = BUNITS*16B (pre path)
template<int AUNITS, int BUNITS>
__device__ __forceinline__ void stage_chunk(const unsigned short* Ag, int pitchA,
                                            const unsigned short* Bg, int pitchB,
                                            int kb, unsigned short* slot, int tid)
{
#pragma unroll
    for (int v = 0; v < AUNITS / 256; ++v) {
        int e = v * 256 + tid;
        gl16(Ag + (size_t)(e >> 3) * pitchA + kb * 64 + (e & 7) * 8, slot + e * 8);
    }
#pragma unroll
    for (int v = 0; v < BUNITS / 256; ++v) {
        int e = v * 256 + tid;
        gl16(Bg + (size_t)(e >> 3) * pitchB + kb * 64 + (e & 7) * 8,
             slot + AUNITS * 8 + e * 8);
    }
}

// stage one K-range (kr): 3 A-split chunks + 3 B-split chunks into one ring buf
__device__ __forceinline__ void stage6(const unsigned short* Ag,
                                       const unsigned short* Bg,
                                       int kr, unsigned short* buf, int tid)
{
#pragma unroll
    for (int s = 0; s < 3; ++s)
#pragma unroll
        for (int v = 0; v < 2; ++v) {
            int e = v * 256 + tid;
            gl16(Ag + (size_t)(e >> 3) * KP_HS + (s * 8 + kr) * 64 + (e & 7) * 8,
                 buf + s * 4096 + e * 8);
        }
#pragma unroll
    for (int s = 0; s < 3; ++s)
#pragma unroll
        for (int v = 0; v < 2; ++v) {
            int e = v * 256 + tid;
            gl16(Bg + (size_t)(e >> 3) * KP_HS + (s * 8 + kr) * 64 + (e & 7) * 8,
                 buf + 12288 + s * 4096 + e * 8);
        }
}

// ---------------- builders (proven R5) --------------------------------------
__global__ __launch_bounds__(256) void build_Xb(const float* __restrict__ fp,
                                                const float* __restrict__ gt)
{
    const int tid = threadIdx.x;
    const int m  = blockIdx.x * 16 + (tid >> 4);
    const int k8 = (blockIdx.y * 16 + (tid & 15)) * 8;
    const int t = m >> 9, b = m & 511;
    float x[8];
    if (k8 < 512) {
        float4 v0 = *(const float4*)(fp + ((size_t)(b * 32 + t)) * 512 + k8);
        float4 v1 = *(const float4*)(fp + ((size_t)(b * 32 + t)) * 512 + k8 + 4);
        x[0]=v0.x; x[1]=v0.y; x[2]=v0.z; x[3]=v0.w;
        x[4]=v1.x; x[5]=v1.y; x[6]=v1.z; x[7]=v1.w;
    } else if (t > 0) {
        float4 v0 = *(const float4*)(gt + ((size_t)(b * 32 + t - 1)) * 128 + (k8 - 512));
        float4 v1 = *(const float4*)(gt + ((size_t)(b * 32 + t - 1)) * 128 + (k8 - 512) + 4);
        x[0]=v0.x; x[1]=v0.y; x[2]=v0.z; x[3]=v0.w;
        x[4]=v1.x; x[5]=v1.y; x[6]=v1.z; x[7]=v1.w;
    } else {
#pragma unroll
        for (int j = 0; j < 8; ++j) x[j] = 0.f;
    }
    unsigned short s0[8], s1[8], s2[8];
#pragma unroll
    for (int j = 0; j < 8; ++j) split3(x[j], s0[j], s1[j], s2[j]);
    const int u = (k8 >> 3) & 7;
    const int base = (k8 & ~63) + (((u ^ (m & 7))) << 3);
#pragma unroll
    for (int p = 0; p < 6; ++p) {
        ushort8v v;
#pragma unroll
        for (int j = 0; j < 8; ++j)
            v[j] = (c_ipt[p] == 0) ? s0[j] : ((c_ipt[p] == 1) ? s1[j] : s2[j]);
        *(ushort8v*)&g_Xb[m][p * 640 + base] = v;
    }
}

__global__ __launch_bounds__(256) void build_Wb(const float* __restrict__ Wk)
{
    const int tid = threadIdx.x;
    const int np = blockIdx.x * 16 + (tid >> 4);
    const int k8 = (blockIdx.y * 16 + (tid & 15)) * 8;
    const int n = (np & 3) * 512 + (np >> 2);
    float x[8];
#pragma unroll
    for (int j = 0; j < 8; ++j) x[j] = Wk[(size_t)(k8 + j) * 2048 + n];
    unsigned short s0[8], s1[8], s2[8];
#pragma unroll
    for (int j = 0; j < 8; ++j) split3(x[j], s0[j], s1[j], s2[j]);
    const int u = (k8 >> 3) & 7;
    const int base = (k8 & ~63) + (((u ^ (np & 7))) << 3);
#pragma unroll
    for (int p = 0; p < 6; ++p) {
        ushort8v v;
#pragma unroll
        for (int j = 0; j < 8; ++j)
            v[j] = (c_jpt[p] == 0) ? s0[j] : ((c_jpt[p] == 1) ? s1[j] : s2[j]);
        *(ushort8v*)&g_Wb[np][p * 640 + base] = v;
    }
}

__global__ __launch_bounds__(256) void build_Rb(const float* __restrict__ Rk)
{
    const int tid = threadIdx.x;
    const int np = blockIdx.x * 16 + (tid >> 4);
    const int k8 = (blockIdx.y * 16 + (tid & 15)) * 8;
    const int n = (np & 3) * 512 + (np >> 2);
    float x[8];
#pragma unroll
    for (int j = 0; j < 8; ++j) x[j] = Rk[(size_t)(k8 + j) * 2048 + n];
    unsigned short s0[8], s1[8], s2[8];
#pragma unroll
    for (int j = 0; j < 8; ++j) split3(x[j], s0[j], s1[j], s2[j]);
    const int u = (k8 >> 3) & 7;
    const int base = (k8 & ~63) + (((u ^ (np & 7))) << 3);
    ushort8v v0, v1, v2;
#pragma unroll
    for (int j = 0; j < 8; ++j) { v0[j] = s0[j]; v1[j] = s1[j]; v2[j] = s2[j]; }
    *(ushort8v*)&g_Rb[np][0 * 512 + base] = v0;
    *(ushort8v*)&g_Rb[np][1 * 512 + base] = v1;
    *(ushort8v*)&g_Rb[np][2 * 512 + base] = v2;
}

__global__ __launch_bounds__(256) void build_misc(const float* __restrict__ sw,
                                                  const float* __restrict__ bias)
{
    int id = blockIdx.x * 256 + threadIdx.x;
    if (id < 128 * 512) {
        int c = id >> 9, r = id & 511;
        g_swT[c][r] = sw[(size_t)r * 128 + c];
    } else if (id < 128 * 512 + 2048) {
        int np = id - 128 * 512;
        g_bperm[np] = bias[(np & 3) * 512 + (np >> 2)];
    }
}

// ---------------- PRE = x@K + bias (MFMA, counted-vmcnt ring) ----------------
__global__ __launch_bounds__(256, 1) void pre_mfma()
{
    __shared__ __align__(16) char smem[98304];     // 4 slots x 24 KB
    const int tid = threadIdx.x, lane = tid & 63, wave = tid >> 6;
    const int n0 = blockIdx.x * 64, m0 = blockIdx.y * 128;
    const int wr = wave >> 1, wc = wave & 1, l15 = lane & 15, ql = lane >> 4;
    unsigned short* ring = (unsigned short*)smem;
    const unsigned short* Ag = &g_Xb[m0][0];
    const unsigned short* Bg = &g_Wb[n0][0];

    f32x4 acc[4][2];
#pragma unroll
    for (int a = 0; a < 4; ++a)
#pragma unroll
        for (int b = 0; b < 2; ++b) acc[a][b] = (f32x4){0.f, 0.f, 0.f, 0.f};

    stage_chunk<1024, 512>(Ag, KP_PRE, Bg, KP_PRE, 0, ring + 0 * 12288, tid);
    stage_chunk<1024, 512>(Ag, KP_PRE, Bg, KP_PRE, 1, ring + 1 * 12288, tid);
    stage_chunk<1024, 512>(Ag, KP_PRE, Bg, KP_PRE, 2, ring + 2 * 12288, tid);
    for (int c = 0; c < 60; ++c) {
        if (c <= 57)      WAITV(12);
        else if (c == 58) WAITV(6);
        else              WAITV(0);
        SBAR();
        const unsigned short* Ac = ring + (c & 3) * 12288;
        const unsigned short* Bc = Ac + 8192;
#pragma unroll
        for (int sub = 0; sub < 2; ++sub) {
            const int uw = sub * 4 + ql;
            short8v af[4], bfr[2];
#pragma unroll
            for (int fa = 0; fa < 4; ++fa)
                af[fa] = fragld(Ac, wr * 64 + fa * 16 + l15, uw);
#pragma unroll
            for (int fb = 0; fb < 2; ++fb)
                bfr[fb] = fragld(Bc, wc * 32 + fb * 16 + l15, uw);
#pragma unroll
            for (int fa = 0; fa < 4; ++fa)
#pragma unroll
                for (int fb = 0; fb < 2; ++fb)
                    acc[fa][fb] = __builtin_amdgcn_mfma_f32_16x16x32_bf16(
                        af[fa], bfr[fb], acc[fa][fb], 0, 0, 0);
        }
        if (c + 3 < 60)
            stage_chunk<1024, 512>(Ag, KP_PRE, Bg, KP_PRE, c + 3,
                                   ring + ((c + 3) & 3) * 12288, tid);
    }
#pragma unroll
    for (int fa = 0; fa < 4; ++fa)
#pragma unroll
        for (int fb = 0; fb < 2; ++fb) {
            const int np = n0 + wc * 32 + fb * 16 + l15;
            const float bv = g_bperm[np];
#pragma unroll
            for (int q = 0; q < 4; ++q) {
                const int m = m0 + wr * 64 + fa * 16 + ql * 4 + q;
                g_pre[m][np] = acc[fa][fb][q] + bv;
            }
        }
}

// ---------------- persistent recurrence --------------------------------------
__global__ __launch_bounds__(256, 1) void charnn_rec(
    const float* __restrict__ sb,
    float* __restrict__ seq, float* __restrict__ out_h, float* __restrict__ out_c)
{
    __shared__ __align__(16) char smem[147456];    // 3 ring bufs x 48 KB; zbuf alias
    float (*zbuf)[68] = (float (*)[68])smem;
    unsigned short* ring = (unsigned short*)smem;

    const int bi = blockIdx.x, tid = threadIdx.x;
    const int lane = tid & 63, wave = tid >> 6;
    // XCD-aware tile map: XCD x = bi&7 owns 4 Mg x 8 contiguous Ng
    const int x  = bi & 7, jj = bi >> 3;
    const int Mg = ((x & 1) << 2) | (jj & 3);        // 0..7, 4 per XCD
    const int Ng = ((x >> 1) << 3) | (jj >> 2);      // 0..31, 8 contiguous per XCD
    const int m0 = Mg * 64, n0 = Ng * 64;
    const int wr = wave >> 1, wc = wave & 1, l15 = lane & 15, ql = lane >> 4;

    // epilogue ownership: 4 cells (one m-row, 4 consecutive r-locals)
    const int m_e = tid >> 2;            // 0..63
    const int rb4 = (tid & 3) * 4;       // 0,4,8,12
    const int mg = m0 + m_e;
    float cst[4] = {0.f, 0.f, 0.f, 0.f};

    // logits mapping aligned to this block's Mg rows (g_hf stays fabric-local)
    const int rgrp = Mg * 4 + (Ng & 3);  // 0..31
    const int cg   = Ng >> 2;            // 0..7
    // argmax-finalize rows aligned to Mg rows
    const int arow = Mg * 64 + Ng * 2;

    for (int ph = 0; ph < 34; ++ph) {
        // ---- z-MFMA + gates for t = ph ----
        if (ph <= 31) {
            const int t = ph;
            const float* prow = &g_pre[t * 512 + mg][n0];
            // prefetch pre (cold HBM) at phase start; oldest in vmcnt queue
            f32x4 pq0 = *(const f32x4*)(prow + rb4 * 4);
            f32x4 pq1 = *(const f32x4*)(prow + rb4 * 4 + 4);
            f32x4 pq2 = *(const f32x4*)(prow + rb4 * 4 + 8);
            f32x4 pq3 = *(const f32x4*)(prow + rb4 * 4 + 12);

            if (t > 0) {
                f32x4 acc[2][2];
#pragma unroll
                for (int a = 0; a < 2; ++a)
#pragma unroll
                    for (int b = 0; b < 2; ++b) acc[a][b] = (f32x4){0.f, 0.f, 0.f, 0.f};

                const unsigned short* Ag = &g_hs[(t + 1) & 1][m0][0];
                const unsigned short* Bg = &g_Rb[n0][0];
                stage6(Ag, Bg, 0, ring + 0 * 24576, tid);
                stage6(Ag, Bg, 1, ring + 1 * 24576, tid);
#pragma unroll
                for (int kr = 0; kr < 8; ++kr) {
                    if (kr < 6)
                        stage6(Ag, Bg, kr + 2, ring + ((kr + 2) % 3) * 24576, tid);
                    if (kr < 6)       WAITV(24);
                    else if (kr == 6) WAITV(12);
                    else              WAITV(0);
                    SBAR();
                    const unsigned short* Ab = ring + (kr % 3) * 24576;
                    const unsigned short* Bb = Ab + 12288;
#pragma unroll
                    for (int p = 0; p < 6; ++p) {
                        const unsigned short* Ac = Ab + c_ipt[p] * 4096;
                        const unsigned short* Bc = Bb + c_jpt[p] * 4096;
#pragma unroll
                        for (int sub = 0; sub < 2; ++sub) {
                            const int uw = sub * 4 + ql;
                            short8v af[2], bfr[2];
                            af[0]  = fragld(Ac, wr * 32 + l15, uw);
                            af[1]  = fragld(Ac, wr * 32 + 16 + l15, uw);
                            bfr[0] = fragld(Bc, wc * 32 + l15, uw);
                            bfr[1] = fragld(Bc, wc * 32 + 16 + l15, uw);
                            acc[0][0] = __builtin_amdgcn_mfma_f32_16x16x32_bf16(
                                af[0], bfr[0], acc[0][0], 0, 0, 0);
                            acc[0][1] = __builtin_amdgcn_mfma_f32_16x16x32_bf16(
                                af[0], bfr[1], acc[0][1], 0, 0, 0);
                            acc[1][0] = __builtin_amdgcn_mfma_f32_16x16x32_bf16(
                                af[1], bfr[0], acc[1][0], 0, 0, 0);
                            acc[1][1] = __builtin_amdgcn_mfma_f32_16x16x32_bf16(
                                af[1], bfr[1], acc[1][1], 0, 0, 0);
                        }
                    }
                }
                __syncthreads();   // drain ring reads; ring -> zbuf reuse safe
#pragma unroll
                for (int fa = 0; fa < 2; ++fa)
#pragma unroll
                    for (int fb = 0; fb < 2; ++fb)
#pragma unroll
                        for (int q = 0; q < 4; ++q)
                            zbuf[wr * 32 + fa * 16 + ql * 4 + q]
                                [wc * 32 + fb * 16 + l15] = acc[fa][fb][q];
            }
            __syncthreads();

            unsigned short hs0[4], hs1[4], hs2[4];
            float hv4[4];
#pragma unroll
            for (int i = 0; i < 4; ++i) {
                const int rl = rb4 + i;
                float zi, zf, zg, zo;
                if (t > 0) {
                    float4 zq = *(const float4*)&zbuf[m_e][rl * 4];
                    zi = zq.x; zf = zq.y; zg = zq.z; zo = zq.w;
                } else { zi = zf = zg = zo = 0.f; }
                f32x4 pq = (i == 0) ? pq0 : ((i == 1) ? pq1 : ((i == 2) ? pq2 : pq3));
                zi += pq[0]; zf += pq[1]; zg += pq[2]; zo += pq[3];
                float c2 = sigf(zf) * cst[i] + sigf(zi) * tanhf(zg);
                float h2 = sigf(zo) * tanhf(c2);
                cst[i] = c2;
                hv4[i] = h2;
                split3(h2, hs0[i], hs1[i], hs2[i]);
            }
            const int r0g = Ng * 16 + rb4;
            *(float4*)&g_hf[t & 1][(size_t)mg * 512 + r0g] =
                make_float4(hv4[0], hv4[1], hv4[2], hv4[3]);
            if (t == 31) {
                *(float4*)&out_h[(size_t)mg * 512 + r0g] =
                    make_float4(hv4[0], hv4[1], hv4[2], hv4[3]);
                *(float4*)&out_c[(size_t)mg * 512 + r0g] =
                    make_float4(cst[0], cst[1], cst[2], cst[3]);
            }
            // h splits -> g_hs (3 splits, 4 consecutive k' = one 8B store each)
            const int su = ((r0g >> 3) & 7) ^ (mg & 7);
            const int abase = (r0g & ~63) + (su << 3) + (r0g & 7);
#pragma unroll
            for (int i = 0; i < 3; ++i) {
                ushort4v v;
#pragma unroll
                for (int j = 0; j < 4; ++j)
                    v[j] = (i == 0) ? hs0[j] : ((i == 1) ? hs1[j] : hs2[j]);
                *(ushort4v*)&g_hs[t & 1][mg][i * 512 + abase] = v;
            }
        }

        // ---- logits partials for t = ph-1 (f32): 16 rows x 16 cols / block ----
        if (ph >= 1 && ph <= 32) {
            const int tl = ph - 1;
            const int row = rgrp * 16 + (tid >> 4);
            const int col = cg * 16 + (tid & 15);
            const float* hrow = &g_hf[tl & 1][(size_t)row * 512];
            const float* wcol = &g_swT[col][0];
            float s0 = sb[col], s1 = 0.f, s2 = 0.f, s3 = 0.f;
#pragma unroll 8
            for (int k = 0; k < 512; k += 4) {
                float4 hv = *(const float4*)(hrow + k);
                float4 wv = *(const float4*)(wcol + k);
                s0 = fmaf(hv.x, wv.x, s0); s1 = fmaf(hv.y, wv.y, s1);
                s2 = fmaf(hv.z, wv.z, s2); s3 = fmaf(hv.w, wv.w, s3);
            }
            float bv = (s0 + s1) + (s2 + s3); int bidx = col;
#pragma unroll
            for (int m = 1; m < 16; m <<= 1) {
                float ov = __shfl_xor(bv, m, 64);
                int   oi = __shfl_xor(bidx, m, 64);
                if (ov > bv || (ov == bv && oi < bidx)) { bv = ov; bidx = oi; }
            }
            if ((tid & 15) == 0) {
                g_plv[tl & 1][row * 8 + cg] = bv;
                g_pli[tl & 1][row * 8 + cg] = bidx;
            }
        }

        // ---- finalize argmax for t = ph-2 -> one-hot (2 rows/block) ----
        if (ph >= 2 && wave < 2) {
            const int t2 = ph - 2;
            const int row = arow + wave;
            float v; int idx;
            if (lane < 8) {
                v   = g_plv[t2 & 1][row * 8 + lane];
                idx = g_pli[t2 & 1][row * 8 + lane];
            } else { v = -INFINITY; idx = 0x7fffffff; }
#pragma unroll
            for (int m = 1; m < 8; m <<= 1) {
                float ov = __shfl_xor(v, m, 64);
                int   oi = __shfl_xor(idx, m, 64);
                if (ov > v || (ov == v && oi < idx)) { v = ov; idx = oi; }
            }
            int win = __shfl(idx, 0, 64);
            if (lane < 32) {
                int c4 = lane * 4;
                float4 o;
                o.x = (c4 + 0 == win) ? 1.f : 0.f;
                o.y = (c4 + 1 == win) ? 1.f : 0.f;
                o.z = (c4 + 2 == win) ? 1.f : 0.f;
                o.w = (c4 + 3 == win) ? 1.f : 0.f;
                *(float4*)(seq + ((size_t)row * 32 + t2) * 128 + c4) = o;
            }
        }

        // ---- grid barrier (two-level, relaxed polls, hoisted fences) ----
        if (ph < 33) {
            __syncthreads();
            if (tid == 0) {
                __builtin_amdgcn_fence(__ATOMIC_RELEASE, "agent");
                __hip_atomic_fetch_add(&g_cnt[(bi & 7) * 16], 1u,
                                       __ATOMIC_RELAXED, __HIP_MEMORY_SCOPE_AGENT);
            }
            if (bi == 0) {
                if (tid < 8) {
                    const unsigned tgt = 32u * (unsigned)(ph + 1);
                    while (__hip_atomic_load(&g_cnt[tid * 16], __ATOMIC_RELAXED,
                                             __HIP_MEMORY_SCOPE_AGENT) < tgt)
                        __builtin_amdgcn_s_sleep(2);
                }
                __syncthreads();
                if (tid == 0)
                    __hip_atomic_store(&g_release, (unsigned)(ph + 1),
                                       __ATOMIC_RELAXED, __HIP_MEMORY_SCOPE_AGENT);
            }
            if (tid == 0) {
                while (__hip_atomic_load(&g_release, __ATOMIC_RELAXED,
                                         __HIP_MEMORY_SCOPE_AGENT) < (unsigned)(ph + 1))
                    __builtin_amdgcn_s_sleep(2);
                __builtin_amdgcn_fence(__ATOMIC_ACQUIRE, "agent");
            }
            __syncthreads();
        }
    }
}

// ---------------------------------------------------------------------------
extern "C" void kernel_launch(void* const* d_in, const int* in_sizes, int n_in,
                              void* d_out, int out_size, void* d_ws, size_t ws_size,
                              hipStream_t stream)
{
    const float* fp   = (const float*)d_in[0];  // f_pool       [512,32,512]
    const float* gt   = (const float*)d_in[1];  // ground_truth [512,32,128]
    const float* Wk   = (const float*)d_in[2];  // kernel       [640,2048]
    const float* Rk   = (const float*)d_in[3];  // rec_kernel   [512,2048]
    const float* bias = (const float*)d_in[4];  // [2048]
    const float* sw   = (const float*)d_in[5];  // softmax_w    [512,128]
    const float* sb   = (const float*)d_in[6];  // softmax_b    [128]
    float* seq   = (float*)d_out;                        // [512,32,128]
    float* out_h = seq + (size_t)512 * 32 * 128;         // [512,512]
    float* out_c = out_h + (size_t)512 * 512;            // [512,512]

    hipLaunchKernelGGL(init_counters, dim3(1), dim3(64), 0, stream);
    hipLaunchKernelGGL(build_Xb, dim3(1024, 5), dim3(256), 0, stream, fp, gt);
    hipLaunchKernelGGL(build_Wb, dim3(128, 5), dim3(256), 0, stream, Wk);
    hipLaunchKernelGGL(build_Rb, dim3(128, 4), dim3(256), 0, stream, Rk);
    hipLaunchKernelGGL(build_misc, dim3(264), dim3(256), 0, stream, sw, bias);
    hipLaunchKernelGGL(pre_mfma, dim3(32, 128), dim3(256), 0, stream);
    hipLaunchKernelGGL(charnn_rec, dim3(256), dim3(256), 0, stream,
                       sb, seq, out_h, out_c);
}

// Round 2
// 1843.820 us; speedup vs baseline: 1.1066x; 1.0486x over previous
//
#include <hip/hip_runtime.h>
#include <math.h>

typedef float  f32x4  __attribute__((ext_vector_type(4)));
typedef short  short8v __attribute__((ext_vector_type(8)));
typedef unsigned short ushort8v __attribute__((ext_vector_type(8)));
typedef unsigned short ushort4v __attribute__((ext_vector_type(4)));

#define KP_PRE 3840
#define KP_HS  1536

#define WAITV(N) asm volatile("s_waitcnt vmcnt(" #N ")" ::: "memory")
#define SBAR()   asm volatile("s_barrier" ::: "memory")

// ---------------- persistent device state ----------------------------------
__device__ unsigned short g_Xb[16384][3840];  // pre A (x split-6, swizzled)
__device__ unsigned short g_Wb[2048][3840];   // pre B^T (kernel split-6)
__device__ unsigned short g_Rb[2048][1536];   // z   B^T (rec_kernel, 3 j-splits)
__device__ unsigned short g_hs[2][512][1536]; // h 3 i-splits, ping-pong
__device__ float g_pre[16384][2048];          // x@K + bias (gate-interleaved)
__device__ float g_hf[2][512 * 512];          // h f32, ping-pong
__device__ float g_swT[128][512];             // softmax_w transposed
__device__ float g_bperm[2048];               // bias, gate-interleaved cols
__device__ float g_plv[2][512 * 8];
__device__ int   g_pli[2][512 * 8];
__device__ unsigned g_cnt[128];
__device__ unsigned g_release;

__global__ void init_counters()
{
    int t = threadIdx.x;
    if (t < 8) g_cnt[t * 16] = 0u;
    if (t == 8) g_release = 0u;
}

// ---------------- helpers ---------------------------------------------------
__device__ __forceinline__ unsigned short f2bf(float f) {
    unsigned u = __float_as_uint(f);
    return (unsigned short)((u + 0x7fffu + ((u >> 16) & 1u)) >> 16);
}
__device__ __forceinline__ float bf2f(unsigned short s) {
    return __uint_as_float(((unsigned)s) << 16);
}
__device__ __forceinline__ float sigf(float x) { return 1.f / (1.f + expf(-x)); }

__device__ __forceinline__ void split3(float v, unsigned short& s0,
                                       unsigned short& s1, unsigned short& s2) {
    s0 = f2bf(v); float f0 = bf2f(s0);
    s1 = f2bf(v - f0); float f1 = bf2f(s1);
    s2 = f2bf(v - f0 - f1);
}

// pair tables: products split_i(A) * split_j(B), i+j <= 2
__device__ __constant__ int c_ipt[6] = {0, 0, 1, 0, 1, 2};
__device__ __constant__ int c_jpt[6] = {0, 1, 0, 2, 1, 0};

__device__ __forceinline__ void gl16(const unsigned short* g, unsigned short* l) {
    __builtin_amdgcn_global_load_lds((const __attribute__((address_space(1))) void*)g,
                                     (__attribute__((address_space(3))) void*)l, 16, 0, 0);
}

// LDS tile: [rows][64] bf16, row = 128B, 16B-units XOR-swizzled by (row&7)
__device__ __forceinline__ short8v fragld(const unsigned short* sh, int row, int uw) {
    return *(const short8v*)(sh + row * 64 + ((uw ^ (row & 7)) << 3));
}

// stage one BK=64 chunk into ring slot: A = AUNITS*16B, B = BUNITS*16B (pre path)
template<int AUNITS, int BUNITS>
__device__ __forceinline__ void stage_chunk(const unsigned short* Ag, int pitchA,
                                            const unsigned short* Bg, int pitchB,
                                            int kb, unsigned short* slot, int tid)
{
#pragma unroll
    for (int v = 0; v < AUNITS / 256; ++v) {
        int e = v * 256 + tid;
        gl16(Ag + (size_t)(e >> 3) * pitchA + kb * 64 + (e & 7) * 8, slot + e * 8);
    }
#pragma unroll
    for (int v = 0; v < BUNITS / 256; ++v) {
        int e = v * 256 + tid;
        gl16(Bg + (size_t)(e >> 3) * pitchB + kb * 64 + (e & 7) * 8,
             slot + AUNITS * 8 + e * 8);
    }
}

// stage one K-range (kr): 3 A-split chunks + 3 B-split chunks into one ring buf
__device__ __forceinline__ void stage6(const unsigned short* Ag,
                                       const unsigned short* Bg,
                                       int kr, unsigned short* buf, int tid)
{
#pragma unroll
    for (int s = 0; s < 3; ++s)
#pragma unroll
        for (int v = 0; v < 2; ++v) {
            int e = v * 256 + tid;
            gl16(Ag + (size_t)(e >> 3) * KP_HS + (s * 8 + kr) * 64 + (e & 7) * 8,
                 buf + s * 4096 + e * 8);
        }
#pragma unroll
    for (int s = 0; s < 3; ++s)
#pragma unroll
        for (int v = 0; v < 2; ++v) {
            int e = v * 256 + tid;
            gl16(Bg + (size_t)(e >> 3) * KP_HS + (s * 8 + kr) * 64 + (e & 7) * 8,
                 buf + 12288 + s * 4096 + e * 8);
        }
}

// ---------------- builders (proven R5) --------------------------------------
__global__ __launch_bounds__(256) void build_Xb(const float* __restrict__ fp,
                                                const float* __restrict__ gt)
{
    const int tid = threadIdx.x;
    const int m  = blockIdx.x * 16 + (tid >> 4);
    const int k8 = (blockIdx.y * 16 + (tid & 15)) * 8;
    const int t = m >> 9, b = m & 511;
    float x[8];
    if (k8 < 512) {
        float4 v0 = *(const float4*)(fp + ((size_t)(b * 32 + t)) * 512 + k8);
        float4 v1 = *(const float4*)(fp + ((size_t)(b * 32 + t)) * 512 + k8 + 4);
        x[0]=v0.x; x[1]=v0.y; x[2]=v0.z; x[3]=v0.w;
        x[4]=v1.x; x[5]=v1.y; x[6]=v1.z; x[7]=v1.w;
    } else if (t > 0) {
        float4 v0 = *(const float4*)(gt + ((size_t)(b * 32 + t - 1)) * 128 + (k8 - 512));
        float4 v1 = *(const float4*)(gt + ((size_t)(b * 32 + t - 1)) * 128 + (k8 - 512) + 4);
        x[0]=v0.x; x[1]=v0.y; x[2]=v0.z; x[3]=v0.w;
        x[4]=v1.x; x[5]=v1.y; x[6]=v1.z; x[7]=v1.w;
    } else {
#pragma unroll
        for (int j = 0; j < 8; ++j) x[j] = 0.f;
    }
    unsigned short s0[8], s1[8], s2[8];
#pragma unroll
    for (int j = 0; j < 8; ++j) split3(x[j], s0[j], s1[j], s2[j]);
    const int u = (k8 >> 3) & 7;
    const int base = (k8 & ~63) + (((u ^ (m & 7))) << 3);
#pragma unroll
    for (int p = 0; p < 6; ++p) {
        ushort8v v;
#pragma unroll
        for (int j = 0; j < 8; ++j)
            v[j] = (c_ipt[p] == 0) ? s0[j] : ((c_ipt[p] == 1) ? s1[j] : s2[j]);
        *(ushort8v*)&g_Xb[m][p * 640 + base] = v;
    }
}

__global__ __launch_bounds__(256) void build_Wb(const float* __restrict__ Wk)
{
    const int tid = threadIdx.x;
    const int np = blockIdx.x * 16 + (tid >> 4);
    const int k8 = (blockIdx.y * 16 + (tid & 15)) * 8;
    const int n = (np & 3) * 512 + (np >> 2);
    float x[8];
#pragma unroll
    for (int j = 0; j < 8; ++j) x[j] = Wk[(size_t)(k8 + j) * 2048 + n];
    unsigned short s0[8], s1[8], s2[8];
#pragma unroll
    for (int j = 0; j < 8; ++j) split3(x[j], s0[j], s1[j], s2[j]);
    const int u = (k8 >> 3) & 7;
    const int base = (k8 & ~63) + (((u ^ (np & 7))) << 3);
#pragma unroll
    for (int p = 0; p < 6; ++p) {
        ushort8v v;
#pragma unroll
        for (int j = 0; j < 8; ++j)
            v[j] = (c_jpt[p] == 0) ? s0[j] : ((c_jpt[p] == 1) ? s1[j] : s2[j]);
        *(ushort8v*)&g_Wb[np][p * 640 + base] = v;
    }
}

__global__ __launch_bounds__(256) void build_Rb(const float* __restrict__ Rk)
{
    const int tid = threadIdx.x;
    const int np = blockIdx.x * 16 + (tid >> 4);
    const int k8 = (blockIdx.y * 16 + (tid & 15)) * 8;
    const int n = (np & 3) * 512 + (np >> 2);
    float x[8];
#pragma unroll
    for (int j = 0; j < 8; ++j) x[j] = Rk[(size_t)(k8 + j) * 2048 + n];
    unsigned short s0[8], s1[8], s2[8];
#pragma unroll
    for (int j = 0; j < 8; ++j) split3(x[j], s0[j], s1[j], s2[j]);
    const int u = (k8 >> 3) & 7;
    const int base = (k8 & ~63) + (((u ^ (np & 7))) << 3);
    ushort8v v0, v1, v2;
#pragma unroll
    for (int j = 0; j < 8; ++j) { v0[j] = s0[j]; v1[j] = s1[j]; v2[j] = s2[j]; }
    *(ushort8v*)&g_Rb[np][0 * 512 + base] = v0;
    *(ushort8v*)&g_Rb[np][1 * 512 + base] = v1;
    *(ushort8v*)&g_Rb[np][2 * 512 + base] = v2;
}

__global__ __launch_bounds__(256) void build_misc(const float* __restrict__ sw,
                                                  const float* __restrict__ bias)
{
    int id = blockIdx.x * 256 + threadIdx.x;
    if (id < 128 * 512) {
        int c = id >> 9, r = id & 511;
        g_swT[c][r] = sw[(size_t)r * 128 + c];
    } else if (id < 128 * 512 + 2048) {
        int np = id - 128 * 512;
        g_bperm[np] = bias[(np & 3) * 512 + (np >> 2)];
    }
}

// ---------------- PRE = x@K + bias (MFMA, counted-vmcnt ring) ----------------
__global__ __launch_bounds__(256, 1) void pre_mfma()
{
    __shared__ __align__(16) char smem[98304];     // 4 slots x 24 KB
    const int tid = threadIdx.x, lane = tid & 63, wave = tid >> 6;
    const int n0 = blockIdx.x * 64, m0 = blockIdx.y * 128;
    const int wr = wave >> 1, wc = wave & 1, l15 = lane & 15, ql = lane >> 4;
    unsigned short* ring = (unsigned short*)smem;
    const unsigned short* Ag = &g_Xb[m0][0];
    const unsigned short* Bg = &g_Wb[n0][0];

    f32x4 acc[4][2];
#pragma unroll
    for (int a = 0; a < 4; ++a)
#pragma unroll
        for (int b = 0; b < 2; ++b) acc[a][b] = (f32x4){0.f, 0.f, 0.f, 0.f};

    stage_chunk<1024, 512>(Ag, KP_PRE, Bg, KP_PRE, 0, ring + 0 * 12288, tid);
    stage_chunk<1024, 512>(Ag, KP_PRE, Bg, KP_PRE, 1, ring + 1 * 12288, tid);
    stage_chunk<1024, 512>(Ag, KP_PRE, Bg, KP_PRE, 2, ring + 2 * 12288, tid);
    for (int c = 0; c < 60; ++c) {
        if (c <= 57)      WAITV(12);
        else if (c == 58) WAITV(6);
        else              WAITV(0);
        SBAR();
        const unsigned short* Ac = ring + (c & 3) * 12288;
        const unsigned short* Bc = Ac + 8192;
#pragma unroll
        for (int sub = 0; sub < 2; ++sub) {
            const int uw = sub * 4 + ql;
            short8v af[4], bfr[2];
#pragma unroll
            for (int fa = 0; fa < 4; ++fa)
                af[fa] = fragld(Ac, wr * 64 + fa * 16 + l15, uw);
#pragma unroll
            for (int fb = 0; fb < 2; ++fb)
                bfr[fb] = fragld(Bc, wc * 32 + fb * 16 + l15, uw);
#pragma unroll
            for (int fa = 0; fa < 4; ++fa)
#pragma unroll
                for (int fb = 0; fb < 2; ++fb)
                    acc[fa][fb] = __builtin_amdgcn_mfma_f32_16x16x32_bf16(
                        af[fa], bfr[fb], acc[fa][fb], 0, 0, 0);
        }
        if (c + 3 < 60)
            stage_chunk<1024, 512>(Ag, KP_PRE, Bg, KP_PRE, c + 3,
                                   ring + ((c + 3) & 3) * 12288, tid);
    }
#pragma unroll
    for (int fa = 0; fa < 4; ++fa)
#pragma unroll
        for (int fb = 0; fb < 2; ++fb) {
            const int np = n0 + wc * 32 + fb * 16 + l15;
            const float bv = g_bperm[np];
#pragma unroll
            for (int q = 0; q < 4; ++q) {
                const int m = m0 + wr * 64 + fa * 16 + ql * 4 + q;
                g_pre[m][np] = acc[fa][fb][q] + bv;
            }
        }
}

// ---------------- persistent recurrence --------------------------------------
__global__ __launch_bounds__(256, 1) void charnn_rec(
    const float* __restrict__ sb,
    float* __restrict__ seq, float* __restrict__ out_h, float* __restrict__ out_c)
{
    __shared__ __align__(16) char smem[147456];    // 3 ring bufs x 48 KB; zbuf alias
    float (*zbuf)[68] = (float (*)[68])smem;
    unsigned short* ring = (unsigned short*)smem;

    const int bi = blockIdx.x, tid = threadIdx.x;
    const int lane = tid & 63, wave = tid >> 6;
    // XCD-local h: XCD x owns ALL of Mg = x (32 Ng blocks). Every g_hs/g_hf/
    // g_plv byte is produced and consumed on the same XCD. B-panels stream
    // from L3 (clean, read-only) under the counted-vmcnt ring.
    const int Mg = bi & 7;                           // == XCD id (round-robin)
    const int Ng = bi >> 3;                          // 0..31
    const int m0 = Mg * 64, n0 = Ng * 64;
    const int wr = wave >> 1, wc = wave & 1, l15 = lane & 15, ql = lane >> 4;

    // epilogue ownership: 4 cells (one m-row, 4 consecutive r-locals)
    const int m_e = tid >> 2;            // 0..63
    const int rb4 = (tid & 3) * 4;       // 0,4,8,12
    const int mg = m0 + m_e;
    float cst[4] = {0.f, 0.f, 0.f, 0.f};

    // logits mapping aligned to this block's Mg rows (g_hf stays XCD-local)
    const int rgrp = Mg * 4 + (Ng & 3);  // 0..31
    const int cg   = Ng >> 2;            // 0..7
    // argmax-finalize rows aligned to Mg rows
    const int arow = Mg * 64 + Ng * 2;

    // compile-time pair tables (register-array indexing must fold)
    constexpr int ipt[6] = {0, 0, 1, 0, 1, 2};
    constexpr int jpt[6] = {0, 1, 0, 2, 1, 0};

    for (int ph = 0; ph < 34; ++ph) {
        // ---- z-MFMA + gates for t = ph ----
        if (ph <= 31) {
            const int t = ph;
            const float* prow = &g_pre[t * 512 + mg][n0];
            // prefetch pre (cold HBM) at phase start; oldest in vmcnt queue
            f32x4 pq0 = *(const f32x4*)(prow + rb4 * 4);
            f32x4 pq1 = *(const f32x4*)(prow + rb4 * 4 + 4);
            f32x4 pq2 = *(const f32x4*)(prow + rb4 * 4 + 8);
            f32x4 pq3 = *(const f32x4*)(prow + rb4 * 4 + 12);

            if (t > 0) {
                f32x4 acc[2][2];
#pragma unroll
                for (int a = 0; a < 2; ++a)
#pragma unroll
                    for (int b = 0; b < 2; ++b) acc[a][b] = (f32x4){0.f, 0.f, 0.f, 0.f};

                const unsigned short* Ag = &g_hs[(t + 1) & 1][m0][0];
                const unsigned short* Bg = &g_Rb[n0][0];
                stage6(Ag, Bg, 0, ring + 0 * 24576, tid);
                stage6(Ag, Bg, 1, ring + 1 * 24576, tid);
#pragma unroll
                for (int kr = 0; kr < 8; ++kr) {
                    if (kr < 6)
                        stage6(Ag, Bg, kr + 2, ring + ((kr + 2) % 3) * 24576, tid);
                    if (kr < 6)       WAITV(24);
                    else if (kr == 6) WAITV(12);
                    else              WAITV(0);
                    SBAR();
                    const unsigned short* Ab = ring + (kr % 3) * 24576;
                    const unsigned short* Bb = Ab + 12288;
#pragma unroll
                    for (int sub = 0; sub < 2; ++sub) {
                        const int uw = sub * 4 + ql;
                        // register-cache the 3 A-splits and 3 B-splits once,
                        // then run all 6 pairs (24 MFMA) from registers:
                        // halves ds_read_b128 traffic vs per-pair loads.
                        short8v a0[2], a1[2], a2[2], b0[2], b1[2], b2[2];
                        a0[0] = fragld(Ab + 0 * 4096, wr * 32 + l15, uw);
                        a0[1] = fragld(Ab + 0 * 4096, wr * 32 + 16 + l15, uw);
                        a1[0] = fragld(Ab + 1 * 4096, wr * 32 + l15, uw);
                        a1[1] = fragld(Ab + 1 * 4096, wr * 32 + 16 + l15, uw);
                        a2[0] = fragld(Ab + 2 * 4096, wr * 32 + l15, uw);
                        a2[1] = fragld(Ab + 2 * 4096, wr * 32 + 16 + l15, uw);
                        b0[0] = fragld(Bb + 0 * 4096, wc * 32 + l15, uw);
                        b0[1] = fragld(Bb + 0 * 4096, wc * 32 + 16 + l15, uw);
                        b1[0] = fragld(Bb + 1 * 4096, wc * 32 + l15, uw);
                        b1[1] = fragld(Bb + 1 * 4096, wc * 32 + 16 + l15, uw);
                        b2[0] = fragld(Bb + 2 * 4096, wc * 32 + l15, uw);
                        b2[1] = fragld(Bb + 2 * 4096, wc * 32 + 16 + l15, uw);
#pragma unroll
                        for (int p = 0; p < 6; ++p) {
                            const short8v* A2 = (ipt[p] == 0) ? a0 :
                                                ((ipt[p] == 1) ? a1 : a2);
                            const short8v* B2 = (jpt[p] == 0) ? b0 :
                                                ((jpt[p] == 1) ? b1 : b2);
                            acc[0][0] = __builtin_amdgcn_mfma_f32_16x16x32_bf16(
                                A2[0], B2[0], acc[0][0], 0, 0, 0);
                            acc[0][1] = __builtin_amdgcn_mfma_f32_16x16x32_bf16(
                                A2[0], B2[1], acc[0][1], 0, 0, 0);
                            acc[1][0] = __builtin_amdgcn_mfma_f32_16x16x32_bf16(
                                A2[1], B2[0], acc[1][0], 0, 0, 0);
                            acc[1][1] = __builtin_amdgcn_mfma_f32_16x16x32_bf16(
                                A2[1], B2[1], acc[1][1], 0, 0, 0);
                        }
                    }
                }
                __syncthreads();   // drain ring reads; ring -> zbuf reuse safe
#pragma unroll
                for (int fa = 0; fa < 2; ++fa)
#pragma unroll
                    for (int fb = 0; fb < 2; ++fb)
#pragma unroll
                        for (int q = 0; q < 4; ++q)
                            zbuf[wr * 32 + fa * 16 + ql * 4 + q]
                                [wc * 32 + fb * 16 + l15] = acc[fa][fb][q];
            }
            __syncthreads();

            unsigned short hs0[4], hs1[4], hs2[4];
            float hv4[4];
#pragma unroll
            for (int i = 0; i < 4; ++i) {
                const int rl = rb4 + i;
                float zi, zf, zg, zo;
                if (t > 0) {
                    float4 zq = *(const float4*)&zbuf[m_e][rl * 4];
                    zi = zq.x; zf = zq.y; zg = zq.z; zo = zq.w;
                } else { zi = zf = zg = zo = 0.f; }
                f32x4 pq = (i == 0) ? pq0 : ((i == 1) ? pq1 : ((i == 2) ? pq2 : pq3));
                zi += pq[0]; zf += pq[1]; zg += pq[2]; zo += pq[3];
                float c2 = sigf(zf) * cst[i] + sigf(zi) * tanhf(zg);
                float h2 = sigf(zo) * tanhf(c2);
                cst[i] = c2;
                hv4[i] = h2;
                split3(h2, hs0[i], hs1[i], hs2[i]);
            }
            const int r0g = Ng * 16 + rb4;
            *(float4*)&g_hf[t & 1][(size_t)mg * 512 + r0g] =
                make_float4(hv4[0], hv4[1], hv4[2], hv4[3]);
            if (t == 31) {
                *(float4*)&out_h[(size_t)mg * 512 + r0g] =
                    make_float4(hv4[0], hv4[1], hv4[2], hv4[3]);
                *(float4*)&out_c[(size_t)mg * 512 + r0g] =
                    make_float4(cst[0], cst[1], cst[2], cst[3]);
            }
            // h splits -> g_hs (3 splits, 4 consecutive k' = one 8B store each)
            const int su = ((r0g >> 3) & 7) ^ (mg & 7);
            const int abase = (r0g & ~63) + (su << 3) + (r0g & 7);
#pragma unroll
            for (int i = 0; i < 3; ++i) {
                ushort4v v;
#pragma unroll
                for (int j = 0; j < 4; ++j)
                    v[j] = (i == 0) ? hs0[j] : ((i == 1) ? hs1[j] : hs2[j]);
                *(ushort4v*)&g_hs[t & 1][mg][i * 512 + abase] = v;
            }
        }

        // ---- logits partials for t = ph-1 (f32): 16 rows x 16 cols / block ----
        if (ph >= 1 && ph <= 32) {
            const int tl = ph - 1;
            const int row = rgrp * 16 + (tid >> 4);
            const int col = cg * 16 + (tid & 15);
            const float* hrow = &g_hf[tl & 1][(size_t)row * 512];
            const float* wcol = &g_swT[col][0];
            float s0 = sb[col], s1 = 0.f, s2 = 0.f, s3 = 0.f;
#pragma unroll 8
            for (int k = 0; k < 512; k += 4) {
                float4 hv = *(const float4*)(hrow + k);
                float4 wv = *(const float4*)(wcol + k);
                s0 = fmaf(hv.x, wv.x, s0); s1 = fmaf(hv.y, wv.y, s1);
                s2 = fmaf(hv.z, wv.z, s2); s3 = fmaf(hv.w, wv.w, s3);
            }
            float bv = (s0 + s1) + (s2 + s3); int bidx = col;
#pragma unroll
            for (int m = 1; m < 16; m <<= 1) {
                float ov = __shfl_xor(bv, m, 64);
                int   oi = __shfl_xor(bidx, m, 64);
                if (ov > bv || (ov == bv && oi < bidx)) { bv = ov; bidx = oi; }
            }
            if ((tid & 15) == 0) {
                g_plv[tl & 1][row * 8 + cg] = bv;
                g_pli[tl & 1][row * 8 + cg] = bidx;
            }
        }

        // ---- finalize argmax for t = ph-2 -> one-hot (2 rows/block) ----
        if (ph >= 2 && wave < 2) {
            const int t2 = ph - 2;
            const int row = arow + wave;
            float v; int idx;
            if (lane < 8) {
                v   = g_plv[t2 & 1][row * 8 + lane];
                idx = g_pli[t2 & 1][row * 8 + lane];
            } else { v = -INFINITY; idx = 0x7fffffff; }
#pragma unroll
            for (int m = 1; m < 8; m <<= 1) {
                float ov = __shfl_xor(v, m, 64);
                int   oi = __shfl_xor(idx, m, 64);
                if (ov > v || (ov == v && oi < idx)) { v = ov; idx = oi; }
            }
            int win = __shfl(idx, 0, 64);
            if (lane < 32) {
                int c4 = lane * 4;
                float4 o;
                o.x = (c4 + 0 == win) ? 1.f : 0.f;
                o.y = (c4 + 1 == win) ? 1.f : 0.f;
                o.z = (c4 + 2 == win) ? 1.f : 0.f;
                o.w = (c4 + 3 == win) ? 1.f : 0.f;
                *(float4*)(seq + ((size_t)row * 32 + t2) * 128 + c4) = o;
            }
        }

        // ---- grid barrier (two-level, relaxed polls, hoisted fences) ----
        if (ph < 33) {
            __syncthreads();
            if (tid == 0) {
                __builtin_amdgcn_fence(__ATOMIC_RELEASE, "agent");
                __hip_atomic_fetch_add(&g_cnt[(bi & 7) * 16], 1u,
                                       __ATOMIC_RELAXED, __HIP_MEMORY_SCOPE_AGENT);
            }
            if (bi == 0) {
                if (tid < 8) {
                    const unsigned tgt = 32u * (unsigned)(ph + 1);
                    while (__hip_atomic_load(&g_cnt[tid * 16], __ATOMIC_RELAXED,
                                             __HIP_MEMORY_SCOPE_AGENT) < tgt)
                        __builtin_amdgcn_s_sleep(2);
                }
                __syncthreads();
                if (tid == 0)
                    __hip_atomic_store(&g_release, (unsigned)(ph + 1),
                                       __ATOMIC_RELAXED, __HIP_MEMORY_SCOPE_AGENT);
            }
            if (tid == 0) {
                while (__hip_atomic_load(&g_release, __ATOMIC_RELAXED,
                                         __HIP_MEMORY_SCOPE_AGENT) < (unsigned)(ph + 1))
                    __builtin_amdgcn_s_sleep(2);
                __builtin_amdgcn_fence(__ATOMIC_ACQUIRE, "agent");
            }
            __syncthreads();
        }
    }
}

// ---------------------------------------------------------------------------
extern "C" void kernel_launch(void* const* d_in, const int* in_sizes, int n_in,
                              void* d_out, int out_size, void* d_ws, size_t ws_size,
                              hipStream_t stream)
{
    const float* fp   = (const float*)d_in[0];  // f_pool       [512,32,512]
    const float* gt   = (const float*)d_in[1];  // ground_truth [512,32,128]
    const float* Wk   = (const float*)d_in[2];  // kernel       [640,2048]
    const float* Rk   = (const float*)d_in[3];  // rec_kernel   [512,2048]
    const float* bias = (const float*)d_in[4];  // [2048]
    const float* sw   = (const float*)d_in[5];  // softmax_w    [512,128]
    const float* sb   = (const float*)d_in[6];  // softmax_b    [128]
    float* seq   = (float*)d_out;                        // [512,32,128]
    float* out_h = seq + (size_t)512 * 32 * 128;         // [512,512]
    float* out_c = out_h + (size_t)512 * 512;            // [512,512]

    hipLaunchKernelGGL(init_counters, dim3(1), dim3(64), 0, stream);
    hipLaunchKernelGGL(build_Xb, dim3(1024, 5), dim3(256), 0, stream, fp, gt);
    hipLaunchKernelGGL(build_Wb, dim3(128, 5), dim3(256), 0, stream, Wk);
    hipLaunchKernelGGL(build_Rb, dim3(128, 4), dim3(256), 0, stream, Rk);
    hipLaunchKernelGGL(build_misc, dim3(264), dim3(256), 0, stream, sw, bias);
    hipLaunchKernelGGL(pre_mfma, dim3(32, 128), dim3(256), 0, stream);
    hipLaunchKernelGGL(charnn_rec, dim3(256), dim3(256), 0, stream,
                       sb, seq, out_h, out_c);
}

// Round 3
// 1807.352 us; speedup vs baseline: 1.1290x; 1.0202x over previous
//
#include <hip/hip_runtime.h>
#include <math.h>

typedef float  f32x4  __attribute__((ext_vector_type(4)));
typedef short  short8v __attribute__((ext_vector_type(8)));
typedef unsigned short ushort8v __attribute__((ext_vector_type(8)));
typedef unsigned short ushort4v __attribute__((ext_vector_type(4)));

#define KP_PRE 3840
#define KP_HS  1536

#define WAITV(N) asm volatile("s_waitcnt vmcnt(" #N ")" ::: "memory")
#define SBAR()   asm volatile("s_barrier" ::: "memory")

// ---------------- persistent device state ----------------------------------
__device__ unsigned short g_Xb[16384][3840];  // pre A (x split-6, swizzled)
__device__ unsigned short g_Wb[2048][3840];   // pre B^T (kernel split-6)
__device__ unsigned short g_Rb[2048][1536];   // z   B^T (rec_kernel, 3 j-splits)
__device__ unsigned short g_hs[2][512][1536]; // h 3 i-splits, ping-pong
__device__ float g_pre[16384][2048];          // x@K + bias (gate-interleaved)
__device__ float g_hf[2][512 * 512];          // h f32, ping-pong
__device__ float g_swT[128][512];             // softmax_w transposed
__device__ float g_bperm[2048];               // bias, gate-interleaved cols
__device__ float g_plv[2][512 * 8];
__device__ int   g_pli[2][512 * 8];
__device__ unsigned g_cnt[128];
__device__ unsigned g_release;

__global__ void init_counters()
{
    int t = threadIdx.x;
    if (t < 8) g_cnt[t * 16] = 0u;
    if (t == 8) g_release = 0u;
}

// ---------------- helpers ---------------------------------------------------
__device__ __forceinline__ unsigned short f2bf(float f) {
    unsigned u = __float_as_uint(f);
    return (unsigned short)((u + 0x7fffu + ((u >> 16) & 1u)) >> 16);
}
__device__ __forceinline__ float bf2f(unsigned short s) {
    return __uint_as_float(((unsigned)s) << 16);
}
__device__ __forceinline__ float sigf(float x) { return 1.f / (1.f + expf(-x)); }

__device__ __forceinline__ void split3(float v, unsigned short& s0,
                                       unsigned short& s1, unsigned short& s2) {
    s0 = f2bf(v); float f0 = bf2f(s0);
    s1 = f2bf(v - f0); float f1 = bf2f(s1);
    s2 = f2bf(v - f0 - f1);
}

// pair tables: products split_i(A) * split_j(B), i+j <= 2
__device__ __constant__ int c_ipt[6] = {0, 0, 1, 0, 1, 2};
__device__ __constant__ int c_jpt[6] = {0, 1, 0, 2, 1, 0};

__device__ __forceinline__ void gl16(const unsigned short* g, unsigned short* l) {
    __builtin_amdgcn_global_load_lds((const __attribute__((address_space(1))) void*)g,
                                     (__attribute__((address_space(3))) void*)l, 16, 0, 0);
}

// LDS tile: [rows][64] bf16, row = 128B, 16B-units XOR-swizzled by (row&7)
__device__ __forceinline__ short8v fragld(const unsigned short* sh, int row, int uw) {
    return *(const short8v*)(sh + row * 64 + ((uw ^ (row & 7)) << 3));
}

// stage one BK=64 chunk into ring slot: A = AUNITS*16B, B = BUNITS*16B (pre path)
template<int AUNITS, int BUNITS>
__device__ __forceinline__ void stage_chunk(const unsigned short* Ag, int pitchA,
                                            const unsigned short* Bg, int pitchB,
                                            int kb, unsigned short* slot, int tid)
{
#pragma unroll
    for (int v = 0; v < AUNITS / 256; ++v) {
        int e = v * 256 + tid;
        gl16(Ag + (size_t)(e >> 3) * pitchA + kb * 64 + (e & 7) * 8, slot + e * 8);
    }
#pragma unroll
    for (int v = 0; v < BUNITS / 256; ++v) {
        int e = v * 256 + tid;
        gl16(Bg + (size_t)(e >> 3) * pitchB + kb * 64 + (e & 7) * 8,
             slot + AUNITS * 8 + e * 8);
    }
}

// stage one K-range (kr): 3 A-split chunks + 3 B-split chunks into one ring buf
__device__ __forceinline__ void stage6(const unsigned short* Ag,
                                       const unsigned short* Bg,
                                       int kr, unsigned short* buf, int tid)
{
#pragma unroll
    for (int s = 0; s < 3; ++s)
#pragma unroll
        for (int v = 0; v < 2; ++v) {
            int e = v * 256 + tid;
            gl16(Ag + (size_t)(e >> 3) * KP_HS + (s * 8 + kr) * 64 + (e & 7) * 8,
                 buf + s * 4096 + e * 8);
        }
#pragma unroll
    for (int s = 0; s < 3; ++s)
#pragma unroll
        for (int v = 0; v < 2; ++v) {
            int e = v * 256 + tid;
            gl16(Bg + (size_t)(e >> 3) * KP_HS + (s * 8 + kr) * 64 + (e & 7) * 8,
                 buf + 12288 + s * 4096 + e * 8);
        }
}

// ---------------- builders (proven R5) --------------------------------------
__global__ __launch_bounds__(256) void build_Xb(const float* __restrict__ fp,
                                                const float* __restrict__ gt)
{
    const int tid = threadIdx.x;
    const int m  = blockIdx.x * 16 + (tid >> 4);
    const int k8 = (blockIdx.y * 16 + (tid & 15)) * 8;
    const int t = m >> 9, b = m & 511;
    float x[8];
    if (k8 < 512) {
        float4 v0 = *(const float4*)(fp + ((size_t)(b * 32 + t)) * 512 + k8);
        float4 v1 = *(const float4*)(fp + ((size_t)(b * 32 + t)) * 512 + k8 + 4);
        x[0]=v0.x; x[1]=v0.y; x[2]=v0.z; x[3]=v0.w;
        x[4]=v1.x; x[5]=v1.y; x[6]=v1.z; x[7]=v1.w;
    } else if (t > 0) {
        float4 v0 = *(const float4*)(gt + ((size_t)(b * 32 + t - 1)) * 128 + (k8 - 512));
        float4 v1 = *(const float4*)(gt + ((size_t)(b * 32 + t - 1)) * 128 + (k8 - 512) + 4);
        x[0]=v0.x; x[1]=v0.y; x[2]=v0.z; x[3]=v0.w;
        x[4]=v1.x; x[5]=v1.y; x[6]=v1.z; x[7]=v1.w;
    } else {
#pragma unroll
        for (int j = 0; j < 8; ++j) x[j] = 0.f;
    }
    unsigned short s0[8], s1[8], s2[8];
#pragma unroll
    for (int j = 0; j < 8; ++j) split3(x[j], s0[j], s1[j], s2[j]);
    const int u = (k8 >> 3) & 7;
    const int base = (k8 & ~63) + (((u ^ (m & 7))) << 3);
#pragma unroll
    for (int p = 0; p < 6; ++p) {
        ushort8v v;
#pragma unroll
        for (int j = 0; j < 8; ++j)
            v[j] = (c_ipt[p] == 0) ? s0[j] : ((c_ipt[p] == 1) ? s1[j] : s2[j]);
        *(ushort8v*)&g_Xb[m][p * 640 + base] = v;
    }
}

__global__ __launch_bounds__(256) void build_Wb(const float* __restrict__ Wk)
{
    const int tid = threadIdx.x;
    const int np = blockIdx.x * 16 + (tid >> 4);
    const int k8 = (blockIdx.y * 16 + (tid & 15)) * 8;
    const int n = (np & 3) * 512 + (np >> 2);
    float x[8];
#pragma unroll
    for (int j = 0; j < 8; ++j) x[j] = Wk[(size_t)(k8 + j) * 2048 + n];
    unsigned short s0[8], s1[8], s2[8];
#pragma unroll
    for (int j = 0; j < 8; ++j) split3(x[j], s0[j], s1[j], s2[j]);
    const int u = (k8 >> 3) & 7;
    const int base = (k8 & ~63) + (((u ^ (np & 7))) << 3);
#pragma unroll
    for (int p = 0; p < 6; ++p) {
        ushort8v v;
#pragma unroll
        for (int j = 0; j < 8; ++j)
            v[j] = (c_jpt[p] == 0) ? s0[j] : ((c_jpt[p] == 1) ? s1[j] : s2[j]);
        *(ushort8v*)&g_Wb[np][p * 640 + base] = v;
    }
}

__global__ __launch_bounds__(256) void build_Rb(const float* __restrict__ Rk)
{
    const int tid = threadIdx.x;
    const int np = blockIdx.x * 16 + (tid >> 4);
    const int k8 = (blockIdx.y * 16 + (tid & 15)) * 8;
    const int n = (np & 3) * 512 + (np >> 2);
    float x[8];
#pragma unroll
    for (int j = 0; j < 8; ++j) x[j] = Rk[(size_t)(k8 + j) * 2048 + n];
    unsigned short s0[8], s1[8], s2[8];
#pragma unroll
    for (int j = 0; j < 8; ++j) split3(x[j], s0[j], s1[j], s2[j]);
    const int u = (k8 >> 3) & 7;
    const int base = (k8 & ~63) + (((u ^ (np & 7))) << 3);
    ushort8v v0, v1, v2;
#pragma unroll
    for (int j = 0; j < 8; ++j) { v0[j] = s0[j]; v1[j] = s1[j]; v2[j] = s2[j]; }
    *(ushort8v*)&g_Rb[np][0 * 512 + base] = v0;
    *(ushort8v*)&g_Rb[np][1 * 512 + base] = v1;
    *(ushort8v*)&g_Rb[np][2 * 512 + base] = v2;
}

__global__ __launch_bounds__(256) void build_misc(const float* __restrict__ sw,
                                                  const float* __restrict__ bias)
{
    int id = blockIdx.x * 256 + threadIdx.x;
    if (id < 128 * 512) {
        int c = id >> 9, r = id & 511;
        g_swT[c][r] = sw[(size_t)r * 128 + c];
    } else if (id < 128 * 512 + 2048) {
        int np = id - 128 * 512;
        g_bperm[np] = bias[(np & 3) * 512 + (np >> 2)];
    }
}

// ---------------- PRE = x@K + bias (MFMA, counted-vmcnt ring) ----------------
__global__ __launch_bounds__(256, 1) void pre_mfma()
{
    __shared__ __align__(16) char smem[98304];     // 4 slots x 24 KB
    const int tid = threadIdx.x, lane = tid & 63, wave = tid >> 6;
    const int n0 = blockIdx.x * 64, m0 = blockIdx.y * 128;
    const int wr = wave >> 1, wc = wave & 1, l15 = lane & 15, ql = lane >> 4;
    unsigned short* ring = (unsigned short*)smem;
    const unsigned short* Ag = &g_Xb[m0][0];
    const unsigned short* Bg = &g_Wb[n0][0];

    f32x4 acc[4][2];
#pragma unroll
    for (int a = 0; a < 4; ++a)
#pragma unroll
        for (int b = 0; b < 2; ++b) acc[a][b] = (f32x4){0.f, 0.f, 0.f, 0.f};

    stage_chunk<1024, 512>(Ag, KP_PRE, Bg, KP_PRE, 0, ring + 0 * 12288, tid);
    stage_chunk<1024, 512>(Ag, KP_PRE, Bg, KP_PRE, 1, ring + 1 * 12288, tid);
    stage_chunk<1024, 512>(Ag, KP_PRE, Bg, KP_PRE, 2, ring + 2 * 12288, tid);
    for (int c = 0; c < 60; ++c) {
        if (c <= 57)      WAITV(12);
        else if (c == 58) WAITV(6);
        else              WAITV(0);
        SBAR();
        const unsigned short* Ac = ring + (c & 3) * 12288;
        const unsigned short* Bc = Ac + 8192;
#pragma unroll
        for (int sub = 0; sub < 2; ++sub) {
            const int uw = sub * 4 + ql;
            short8v af[4], bfr[2];
#pragma unroll
            for (int fa = 0; fa < 4; ++fa)
                af[fa] = fragld(Ac, wr * 64 + fa * 16 + l15, uw);
#pragma unroll
            for (int fb = 0; fb < 2; ++fb)
                bfr[fb] = fragld(Bc, wc * 32 + fb * 16 + l15, uw);
#pragma unroll
            for (int fa = 0; fa < 4; ++fa)
#pragma unroll
                for (int fb = 0; fb < 2; ++fb)
                    acc[fa][fb] = __builtin_amdgcn_mfma_f32_16x16x32_bf16(
                        af[fa], bfr[fb], acc[fa][fb], 0, 0, 0);
        }
        if (c + 3 < 60)
            stage_chunk<1024, 512>(Ag, KP_PRE, Bg, KP_PRE, c + 3,
                                   ring + ((c + 3) & 3) * 12288, tid);
    }
#pragma unroll
    for (int fa = 0; fa < 4; ++fa)
#pragma unroll
        for (int fb = 0; fb < 2; ++fb) {
            const int np = n0 + wc * 32 + fb * 16 + l15;
            const float bv = g_bperm[np];
#pragma unroll
            for (int q = 0; q < 4; ++q) {
                const int m = m0 + wr * 64 + fa * 16 + ql * 4 + q;
                g_pre[m][np] = acc[fa][fb][q] + bv;
            }
        }
}

// ---------------- persistent recurrence --------------------------------------
__global__ __launch_bounds__(256, 1) void charnn_rec(
    const float* __restrict__ sb,
    float* __restrict__ seq, float* __restrict__ out_h, float* __restrict__ out_c)
{
    __shared__ __align__(16) char smem[147456];    // 3 ring bufs x 48 KB; zbuf alias
    float (*zbuf)[68] = (float (*)[68])smem;
    unsigned short* ring = (unsigned short*)smem;

    const int bi = blockIdx.x, tid = threadIdx.x;
    const int lane = tid & 63, wave = tid >> 6;
    // XCD-pair map: XCD x = 2P+e hosts Mg in {2P,2P+1} x Ng in [16e,16e+16).
    // B footprint per XCD = 16 panels x 196 KB = 3.07 MB < 4 MiB L2 ->
    // rec_kernel splits become L2-resident after step 1 (read-only, the
    // per-phase acquire fence provably doesn't evict clean lines - R2 data).
    // Cross-XCD traffic shrinks to the partner-half of A (~196 KB/XCD/step).
    const int x  = bi & 7, jj = bi >> 3;
    const int P  = x >> 1, e = x & 1;
    const int Mg = 2 * P + (jj & 1);                 // 0..7
    const int Ng = e * 16 + (jj >> 1);               // 0..31
    const int m0 = Mg * 64, n0 = Ng * 64;
    const int wr = wave >> 1, wc = wave & 1, l15 = lane & 15, ql = lane >> 4;

    // epilogue ownership: 4 cells (one m-row, 4 consecutive r-locals)
    const int m_e = tid >> 2;            // 0..63
    const int rb4 = (tid & 3) * 4;       // 0,4,8,12
    const int mg = m0 + m_e;
    float cst[4] = {0.f, 0.f, 0.f, 0.f};

    // logits mapping aligned to this block's PAIR rows (g_hf stays pair-local):
    // pair P has 64 blocks (q = e*32 + jj in 0..63) covering 128 rows x 8 cg.
    const int q    = e * 32 + jj;        // 0..63 within pair
    const int rgrp = 8 * P + (q & 7);    // 16-row group within pair rows
    const int cg   = q >> 3;             // 0..7
    // argmax-finalize rows aligned to pair rows
    const int arow = 128 * P + q * 2;

    // compile-time pair tables (register-array indexing must fold)
    constexpr int ipt[6] = {0, 0, 1, 0, 1, 2};
    constexpr int jpt[6] = {0, 1, 0, 2, 1, 0};

    for (int ph = 0; ph < 34; ++ph) {
        // ---- z-MFMA + gates for t = ph ----
        if (ph <= 31) {
            const int t = ph;
            const float* prow = &g_pre[t * 512 + mg][n0];
            // prefetch pre (cold HBM) at phase start; oldest in vmcnt queue
            f32x4 pq0 = *(const f32x4*)(prow + rb4 * 4);
            f32x4 pq1 = *(const f32x4*)(prow + rb4 * 4 + 4);
            f32x4 pq2 = *(const f32x4*)(prow + rb4 * 4 + 8);
            f32x4 pq3 = *(const f32x4*)(prow + rb4 * 4 + 12);

            if (t > 0) {
                f32x4 acc[2][2];
#pragma unroll
                for (int a = 0; a < 2; ++a)
#pragma unroll
                    for (int b = 0; b < 2; ++b) acc[a][b] = (f32x4){0.f, 0.f, 0.f, 0.f};

                const unsigned short* Ag = &g_hs[(t + 1) & 1][m0][0];
                const unsigned short* Bg = &g_Rb[n0][0];
                stage6(Ag, Bg, 0, ring + 0 * 24576, tid);
                stage6(Ag, Bg, 1, ring + 1 * 24576, tid);
#pragma unroll
                for (int kr = 0; kr < 8; ++kr) {
                    if (kr < 6)
                        stage6(Ag, Bg, kr + 2, ring + ((kr + 2) % 3) * 24576, tid);
                    if (kr < 6)       WAITV(24);
                    else if (kr == 6) WAITV(12);
                    else              WAITV(0);
                    SBAR();
                    const unsigned short* Ab = ring + (kr % 3) * 24576;
                    const unsigned short* Bb = Ab + 12288;
#pragma unroll
                    for (int sub = 0; sub < 2; ++sub) {
                        const int uw = sub * 4 + ql;
                        // register-cache the 3 A-splits and 3 B-splits once,
                        // then run all 6 pairs (24 MFMA) from registers:
                        // halves ds_read_b128 traffic vs per-pair loads.
                        short8v a0[2], a1[2], a2[2], b0[2], b1[2], b2[2];
                        a0[0] = fragld(Ab + 0 * 4096, wr * 32 + l15, uw);
                        a0[1] = fragld(Ab + 0 * 4096, wr * 32 + 16 + l15, uw);
                        a1[0] = fragld(Ab + 1 * 4096, wr * 32 + l15, uw);
                        a1[1] = fragld(Ab + 1 * 4096, wr * 32 + 16 + l15, uw);
                        a2[0] = fragld(Ab + 2 * 4096, wr * 32 + l15, uw);
                        a2[1] = fragld(Ab + 2 * 4096, wr * 32 + 16 + l15, uw);
                        b0[0] = fragld(Bb + 0 * 4096, wc * 32 + l15, uw);
                        b0[1] = fragld(Bb + 0 * 4096, wc * 32 + 16 + l15, uw);
                        b1[0] = fragld(Bb + 1 * 4096, wc * 32 + l15, uw);
                        b1[1] = fragld(Bb + 1 * 4096, wc * 32 + 16 + l15, uw);
                        b2[0] = fragld(Bb + 2 * 4096, wc * 32 + l15, uw);
                        b2[1] = fragld(Bb + 2 * 4096, wc * 32 + 16 + l15, uw);
#pragma unroll
                        for (int p = 0; p < 6; ++p) {
                            const short8v* A2 = (ipt[p] == 0) ? a0 :
                                                ((ipt[p] == 1) ? a1 : a2);
                            const short8v* B2 = (jpt[p] == 0) ? b0 :
                                                ((jpt[p] == 1) ? b1 : b2);
                            acc[0][0] = __builtin_amdgcn_mfma_f32_16x16x32_bf16(
                                A2[0], B2[0], acc[0][0], 0, 0, 0);
                            acc[0][1] = __builtin_amdgcn_mfma_f32_16x16x32_bf16(
                                A2[0], B2[1], acc[0][1], 0, 0, 0);
                            acc[1][0] = __builtin_amdgcn_mfma_f32_16x16x32_bf16(
                                A2[1], B2[0], acc[1][0], 0, 0, 0);
                            acc[1][1] = __builtin_amdgcn_mfma_f32_16x16x32_bf16(
                                A2[1], B2[1], acc[1][1], 0, 0, 0);
                        }
                    }
                }
                __syncthreads();   // drain ring reads; ring -> zbuf reuse safe
#pragma unroll
                for (int fa = 0; fa < 2; ++fa)
#pragma unroll
                    for (int fb = 0; fb < 2; ++fb)
#pragma unroll
                        for (int q2 = 0; q2 < 4; ++q2)
                            zbuf[wr * 32 + fa * 16 + ql * 4 + q2]
                                [wc * 32 + fb * 16 + l15] = acc[fa][fb][q2];
            }
            __syncthreads();

            unsigned short hs0[4], hs1[4], hs2[4];
            float hv4[4];
#pragma unroll
            for (int i = 0; i < 4; ++i) {
                const int rl = rb4 + i;
                float zi, zf, zg, zo;
                if (t > 0) {
                    float4 zq = *(const float4*)&zbuf[m_e][rl * 4];
                    zi = zq.x; zf = zq.y; zg = zq.z; zo = zq.w;
                } else { zi = zf = zg = zo = 0.f; }
                f32x4 pq = (i == 0) ? pq0 : ((i == 1) ? pq1 : ((i == 2) ? pq2 : pq3));
                zi += pq[0]; zf += pq[1]; zg += pq[2]; zo += pq[3];
                float c2 = sigf(zf) * cst[i] + sigf(zi) * tanhf(zg);
                float h2 = sigf(zo) * tanhf(c2);
                cst[i] = c2;
                hv4[i] = h2;
                split3(h2, hs0[i], hs1[i], hs2[i]);
            }
            const int r0g = Ng * 16 + rb4;
            *(float4*)&g_hf[t & 1][(size_t)mg * 512 + r0g] =
                make_float4(hv4[0], hv4[1], hv4[2], hv4[3]);
            if (t == 31) {
                *(float4*)&out_h[(size_t)mg * 512 + r0g] =
                    make_float4(hv4[0], hv4[1], hv4[2], hv4[3]);
                *(float4*)&out_c[(size_t)mg * 512 + r0g] =
                    make_float4(cst[0], cst[1], cst[2], cst[3]);
            }
            // h splits -> g_hs (3 splits, 4 consecutive k' = one 8B store each)
            const int su = ((r0g >> 3) & 7) ^ (mg & 7);
            const int abase = (r0g & ~63) + (su << 3) + (r0g & 7);
#pragma unroll
            for (int i = 0; i < 3; ++i) {
                ushort4v v;
#pragma unroll
                for (int j = 0; j < 4; ++j)
                    v[j] = (i == 0) ? hs0[j] : ((i == 1) ? hs1[j] : hs2[j]);
                *(ushort4v*)&g_hs[t & 1][mg][i * 512 + abase] = v;
            }
        }

        // ---- logits partials for t = ph-1 (f32): 16 rows x 16 cols / block ----
        if (ph >= 1 && ph <= 32) {
            const int tl = ph - 1;
            const int row = rgrp * 16 + (tid >> 4);
            const int col = cg * 16 + (tid & 15);
            const float* hrow = &g_hf[tl & 1][(size_t)row * 512];
            const float* wcol = &g_swT[col][0];
            float s0 = sb[col], s1 = 0.f, s2 = 0.f, s3 = 0.f;
#pragma unroll 8
            for (int k = 0; k < 512; k += 4) {
                float4 hv = *(const float4*)(hrow + k);
                float4 wv = *(const float4*)(wcol + k);
                s0 = fmaf(hv.x, wv.x, s0); s1 = fmaf(hv.y, wv.y, s1);
                s2 = fmaf(hv.z, wv.z, s2); s3 = fmaf(hv.w, wv.w, s3);
            }
            float bv = (s0 + s1) + (s2 + s3); int bidx = col;
#pragma unroll
            for (int m = 1; m < 16; m <<= 1) {
                float ov = __shfl_xor(bv, m, 64);
                int   oi = __shfl_xor(bidx, m, 64);
                if (ov > bv || (ov == bv && oi < bidx)) { bv = ov; bidx = oi; }
            }
            if ((tid & 15) == 0) {
                g_plv[tl & 1][row * 8 + cg] = bv;
                g_pli[tl & 1][row * 8 + cg] = bidx;
            }
        }

        // ---- finalize argmax for t = ph-2 -> one-hot (2 rows/block) ----
        if (ph >= 2 && wave < 2) {
            const int t2 = ph - 2;
            const int row = arow + wave;
            float v; int idx;
            if (lane < 8) {
                v   = g_plv[t2 & 1][row * 8 + lane];
                idx = g_pli[t2 & 1][row * 8 + lane];
            } else { v = -INFINITY; idx = 0x7fffffff; }
#pragma unroll
            for (int m = 1; m < 8; m <<= 1) {
                float ov = __shfl_xor(v, m, 64);
                int   oi = __shfl_xor(idx, m, 64);
                if (ov > v || (ov == v && oi < idx)) { v = ov; idx = oi; }
            }
            int win = __shfl(idx, 0, 64);
            if (lane < 32) {
                int c4 = lane * 4;
                float4 o;
                o.x = (c4 + 0 == win) ? 1.f : 0.f;
                o.y = (c4 + 1 == win) ? 1.f : 0.f;
                o.z = (c4 + 2 == win) ? 1.f : 0.f;
                o.w = (c4 + 3 == win) ? 1.f : 0.f;
                *(float4*)(seq + ((size_t)row * 32 + t2) * 128 + c4) = o;
            }
        }

        // ---- grid barrier (two-level, relaxed polls, hoisted fences) ----
        if (ph < 33) {
            __syncthreads();
            if (tid == 0) {
                __builtin_amdgcn_fence(__ATOMIC_RELEASE, "agent");
                __hip_atomic_fetch_add(&g_cnt[(bi & 7) * 16], 1u,
                                       __ATOMIC_RELAXED, __HIP_MEMORY_SCOPE_AGENT);
            }
            if (bi == 0) {
                if (tid < 8) {
                    const unsigned tgt = 32u * (unsigned)(ph + 1);
                    while (__hip_atomic_load(&g_cnt[tid * 16], __ATOMIC_RELAXED,
                                             __HIP_MEMORY_SCOPE_AGENT) < tgt)
                        __builtin_amdgcn_s_sleep(2);
                }
                __syncthreads();
                if (tid == 0)
                    __hip_atomic_store(&g_release, (unsigned)(ph + 1),
                                       __ATOMIC_RELAXED, __HIP_MEMORY_SCOPE_AGENT);
            }
            if (tid == 0) {
                while (__hip_atomic_load(&g_release, __ATOMIC_RELAXED,
                                         __HIP_MEMORY_SCOPE_AGENT) < (unsigned)(ph + 1))
                    __builtin_amdgcn_s_sleep(2);
                __builtin_amdgcn_fence(__ATOMIC_ACQUIRE, "agent");
            }
            __syncthreads();
        }
    }
}

// ---------------------------------------------------------------------------
extern "C" void kernel_launch(void* const* d_in, const int* in_sizes, int n_in,
                              void* d_out, int out_size, void* d_ws, size_t ws_size,
                              hipStream_t stream)
{
    const float* fp   = (const float*)d_in[0];  // f_pool       [512,32,512]
    const float* gt   = (const float*)d_in[1];  // ground_truth [512,32,128]
    const float* Wk   = (const float*)d_in[2];  // kernel       [640,2048]
    const float* Rk   = (const float*)d_in[3];  // rec_kernel   [512,2048]
    const float* bias = (const float*)d_in[4];  // [2048]
    const float* sw   = (const float*)d_in[5];  // softmax_w    [512,128]
    const float* sb   = (const float*)d_in[6];  // softmax_b    [128]
    float* seq   = (float*)d_out;                        // [512,32,128]
    float* out_h = seq + (size_t)512 * 32 * 128;         // [512,512]
    float* out_c = out_h + (size_t)512 * 512;            // [512,512]

    hipLaunchKernelGGL(init_counters, dim3(1), dim3(64), 0, stream);
    hipLaunchKernelGGL(build_Xb, dim3(1024, 5), dim3(256), 0, stream, fp, gt);
    hipLaunchKernelGGL(build_Wb, dim3(128, 5), dim3(256), 0, stream, Wk);
    hipLaunchKernelGGL(build_Rb, dim3(128, 4), dim3(256), 0, stream, Rk);
    hipLaunchKernelGGL(build_misc, dim3(264), dim3(256), 0, stream, sw, bias);
    hipLaunchKernelGGL(pre_mfma, dim3(32, 128), dim3(256), 0, stream);
    hipLaunchKernelGGL(charnn_rec, dim3(256), dim3(256), 0, stream,
                       sb, seq, out_h, out_c);
}